// Round 7
// baseline (449.480 us; speedup 1.0000x reference)
//
#include <hip/hip_runtime.h>
#include <stdint.h>

#define N 8192
#define D 256
#define LOG2E 1.44269504f

typedef __attribute__((ext_vector_type(4))) float f32x4;
typedef __attribute__((ext_vector_type(8))) short bf16x8;

__device__ __forceinline__ unsigned short f2bf(float f) {
    unsigned u = __float_as_uint(f);
    u += 0x7fff + ((u >> 16) & 1);           // RNE
    return (unsigned short)(u >> 16);
}
__device__ __forceinline__ float leaky(float x) {
    return fmaxf(x, 0.f) + 0.2f * fminf(x, 0.f);
}
__device__ __forceinline__ float exp2_raw(float x) {   // v_exp_f32 = 2^x
    float r;
    asm("v_exp_f32 %0, %1" : "=v"(r) : "v"(x));
    return r;
}
// CK-style block_sync_lds: LDS-ordering barrier that does NOT drain vmcnt,
// so register-destination global prefetches stay in flight across it.
__device__ __forceinline__ void sync_lds() {
    asm volatile("s_waitcnt lgkmcnt(0)\n\ts_barrier" ::: "memory");
}

// ---------------- K1: Wh = x @ W (fp32), also write WhT bf16 [D][N] ----------------
#define K1_BM 16
__global__ __launch_bounds__(256) void k1_gemm(const float* __restrict__ x,
                                               const float* __restrict__ W,
                                               float* __restrict__ Wh,
                                               unsigned short* __restrict__ WhT) {
    __shared__ float xsT[32][20];   // [k][r]
    const int t = threadIdx.x;      // = output column
    const int r0 = blockIdx.x * K1_BM;
    float acc[K1_BM];
#pragma unroll
    for (int i = 0; i < K1_BM; ++i) acc[i] = 0.f;

    const int lr = t >> 3, lks = (t & 7) * 4;   // loader coords (t < 128)
    float4 xv;
    if (t < 128) xv = *(const float4*)(x + (size_t)(r0 + lr) * D + lks);

    for (int k0 = 0; k0 < D; k0 += 32) {
        __syncthreads();
        if (t < 128) {
            xsT[lks + 0][lr] = xv.x; xsT[lks + 1][lr] = xv.y;
            xsT[lks + 2][lr] = xv.z; xsT[lks + 3][lr] = xv.w;
        }
        __syncthreads();
        if (t < 128 && k0 + 32 < D)   // prefetch next K-tile; consumed next iter
            xv = *(const float4*)(x + (size_t)(r0 + lr) * D + k0 + 32 + lks);
#pragma unroll 8
        for (int kk = 0; kk < 32; ++kk) {
            float wv = W[(size_t)(k0 + kk) * D + t];
#pragma unroll
            for (int rc = 0; rc < K1_BM / 4; ++rc) {
                float4 xr = *(const float4*)&xsT[kk][rc * 4];
                acc[rc * 4 + 0] += xr.x * wv;
                acc[rc * 4 + 1] += xr.y * wv;
                acc[rc * 4 + 2] += xr.z * wv;
                acc[rc * 4 + 3] += xr.w * wv;
            }
        }
    }
#pragma unroll
    for (int r = 0; r < K1_BM; ++r) Wh[(size_t)(r0 + r) * D + t] = acc[r];
    unsigned short pk[K1_BM];
#pragma unroll
    for (int r = 0; r < K1_BM; ++r) pk[r] = f2bf(acc[r]);
    uint4* dst = (uint4*)(WhT + (size_t)t * N + r0);
    dst[0] = *(uint4*)&pk[0];
    dst[1] = *(uint4*)&pk[8];
}

// ---------------- K2: e_src / e_dst (wave per row), pre-scaled by log2(e) ----------------
__global__ __launch_bounds__(256) void k2_edot(const float* __restrict__ Wh,
                                               const float* __restrict__ a,
                                               float* __restrict__ e_src,
                                               float* __restrict__ e_dst) {
    const int wave = threadIdx.x >> 6, lane = threadIdx.x & 63;
    const int row = blockIdx.x * 4 + wave;
    float4 wv = *(const float4*)(Wh + (size_t)row * D + lane * 4);
    float4 as = *(const float4*)(a + lane * 4);
    float4 ad = *(const float4*)(a + D + lane * 4);
    float ps = wv.x * as.x + wv.y * as.y + wv.z * as.z + wv.w * as.w;
    float pd = wv.x * ad.x + wv.y * ad.y + wv.z * ad.z + wv.w * ad.w;
#pragma unroll
    for (int m = 1; m < 64; m <<= 1) {
        ps += __shfl_xor(ps, m);
        pd += __shfl_xor(pd, m);
    }
    if (lane == 0) { e_src[row] = ps * LOG2E; e_dst[row] = pd * LOG2E; }
}

// ---------------- K4: masked softmax + PV matmul ----------------
// v8 = v7 core loop (unchanged — LDS-throughput bound at ~75% of the pipe;
// afr traffic is irreducible without an occupancy cliff) + atomic-O epilogue:
//  * O_part (64MB write) + k5 (64MB read) round-trip replaced by
//    unsafeAtomicAdd (native global_atomic_add_f32, LLC-side) into one 8MB O
//    and a 32KB l. Saves ~96MB of HBM traffic (~15us across k4+k5).
//  * rotation de-phasing staggers block-end atomic bursts; each O line gets
//    only 8 owner-adds total (one per j-split) -> low contention.
//  * fp32 add-order changes across splits: ~2^-23 relative jitter only.
//  * requires O,l zeroed before k4: single hipMemsetAsync (graph-legal).
#define BM 64
#define BK 64
#define RB (N / BM)          // 128 row-blocks
#define SPLITS 8             // grid = RB*SPLITS = 1024
#define NITER ((N / SPLITS) / BK)   // 16
#define PSTRIDE 72           // ushorts per P row (144 B, 16B-aligned)
__global__ __launch_bounds__(512, 4) void k4_main(const float* __restrict__ adj,
                                                  const unsigned short* __restrict__ WhT,
                                                  const float* __restrict__ e_src,
                                                  const float* __restrict__ e_dst,
                                                  float* __restrict__ O,
                                                  float* __restrict__ l) {
    __shared__ unsigned short p_lds[2][BM][PSTRIDE];   // 18.4 KB P tile, dbuf
    __shared__ float ed_lds[N / SPLITS];               // 4 KB e_dst slice

    const int t = threadIdx.x;
    const int rb = blockIdx.x >> 3;          // row-block
    const int s  = blockIdx.x & 7;           // j-slice == XCD (round-robin heuristic)
    const int r0 = rb * BM;
    const int j0 = s * (N / SPLITS);
    const int rot = ((blockIdx.x >> 8) * 5) & (NITER - 1);   // de-phasing

    // P-generation coords: 8 threads per row, 8 cols each
    const int pr = t >> 3;            // 0..63
    const int pc = (t & 7) * 8;       // 0..56
    const int gr = r0 + pr;

    const int w = t >> 6;             // wave 0..7 -> output cols w*32..w*32+31
    const int lane = t & 63;
    const int quad = lane >> 4, lo = lane & 15;

    // bank-alias swizzle (bit5 ^= row-bit3), folded into constants:
    const int woff = (pc * 2) ^ ((pr & 8) << 2);                 // P-write byte offset
    const int roff0 = (quad * 16) ^ ((lo & 8) << 2);             // afr read, ks2=0
    const int roff1 = (64 + quad * 16) ^ ((lo & 8) << 2);        // afr read, ks2=1

    const float es = e_src[gr];       // already * LOG2E

    // diagonal bookkeeping: at most one (tile, element) per thread per pass
    const int dcol = gr - j0;
    const int dtile = dcol >> 6;
    const int djj = dcol & 7;
    const bool hd = ((unsigned)dcol < (unsigned)(N / SPLITS)) && ((dcol & 56) == pc);

    f32x4 acc[4][2];
#pragma unroll
    for (int mt = 0; mt < 4; ++mt)
#pragma unroll
        for (int nt = 0; nt < 2; ++nt)
            acc[mt][nt] = (f32x4){0.f, 0.f, 0.f, 0.f};
    float lsum = 0.f;

    const float* adj_row = adj + (size_t)gr * N + j0 + pc;
    // B-fragment base: row (= Wh col) = w*32 + nt*16 + lo, k offset = quad*8
    const unsigned short* wt_base = WhT + (size_t)(w * 32 + lo) * N + j0 + quad * 8;

    auto jtf = [&](int i) {
        int c = (i < NITER) ? i : NITER - 1;
        return (c + rot) & (NITER - 1);
    };

    float4 aA0, aA1;                  // adj buffer A: even logical tiles
    float4 aB0, aB1;                  // adj buffer B: odd logical tiles
    bf16x8 bfr[2][2];                 // [ks2][nt]

    auto mma = [&](int cb) {
        __builtin_amdgcn_s_setprio(1);
#pragma unroll
        for (int ks2 = 0; ks2 < 2; ++ks2) {
            bf16x8 afr[4];
#pragma unroll
            for (int mt = 0; mt < 4; ++mt) {
                const char* arow = (const char*)&p_lds[cb][mt * 16 + lo][0];
                afr[mt] = *(const bf16x8*)(arow + (ks2 ? roff1 : roff0));
            }
#pragma unroll
            for (int nt = 0; nt < 2; ++nt)
#pragma unroll
                for (int mt = 0; mt < 4; ++mt)
                    acc[mt][nt] = __builtin_amdgcn_mfma_f32_16x16x32_bf16(
                        afr[mt], bfr[ks2][nt], acc[mt][nt], 0, 0, 0);
        }
        __builtin_amdgcn_s_setprio(0);
    };
    auto bfr_load = [&](int tile) {
#pragma unroll
        for (int ks2 = 0; ks2 < 2; ++ks2)
#pragma unroll
            for (int nt = 0; nt < 2; ++nt)
                bfr[ks2][nt] = *(const bf16x8*)(wt_base + (size_t)nt * (16 * N) +
                                                tile * BK + ks2 * 32);
    };
    // stage: P for rotated tile `tile` from adj regs + ed_lds -> p_lds[buf]
    auto stage = [&](int tile, int buf, float4 a0, float4 a1) {
        f32x4 e0 = *(const f32x4*)&ed_lds[tile * BK + pc];
        f32x4 e1 = *(const f32x4*)&ed_lds[tile * BK + pc + 4];
        float av[8] = {a0.x, a0.y, a0.z, a0.w, a1.x, a1.y, a1.z, a1.w};
        float ev[8] = {e0[0], e0[1], e0[2], e0[3], e1[0], e1[1], e1[2], e1[3]};
        float pv[8];
#pragma unroll
        for (int jj = 0; jj < 8; ++jj)
            pv[jj] = exp2_raw(leaky(es + ev[jj])) * av[jj];   // adj is exactly 0/1
        if (hd && tile == dtile)      // rare: force-keep the diagonal element
            pv[djj] = exp2_raw(leaky(es + ev[djj]));
#pragma unroll
        for (int jj = 0; jj < 8; ++jj) lsum += pv[jj];
        unsigned wpk[4];
#pragma unroll
        for (int jj = 0; jj < 4; ++jj)
            asm("v_cvt_pk_bf16_f32 %0, %1, %2"
                : "=v"(wpk[jj]) : "v"(pv[2 * jj]), "v"(pv[2 * jj + 1]));
        char* prow = (char*)&p_lds[buf][pr][0];
        *(uint4*)(prow + woff) = *(uint4*)wpk;
    };

    // ---- prologue ----
    {
        ((float2*)ed_lds)[t] = ((const float2*)(e_dst + j0))[t];   // ed slice -> LDS
        const int t0 = jtf(0), t1 = jtf(1), t2 = jtf(2);
        aA0 = *(const float4*)(adj_row + t0 * BK);
        aA1 = *(const float4*)(adj_row + t0 * BK + 4);
        aB0 = *(const float4*)(adj_row + t1 * BK);
        aB1 = *(const float4*)(adj_row + t1 * BK + 4);
        bfr_load(t0);
        __syncthreads();                 // ed_lds visible
        stage(t0, 0, aA0, aA1);
        aA0 = *(const float4*)(adj_row + t2 * BK);         // adj tile 2 -> A
        aA1 = *(const float4*)(adj_row + t2 * BK + 4);
    }
    sync_lds();

    for (int it2 = 0; it2 < NITER / 2; ++it2) {
        // ======== even body: it = 2*it2, cb = 0 ========
        {
            const int it = it2 * 2;
            stage(jtf(it + 1), 1, aB0, aB1);               // consume B (odd tile)
            {
                const int tn3 = jtf(it + 3);
                aB0 = *(const float4*)(adj_row + tn3 * BK);        // refill B
                aB1 = *(const float4*)(adj_row + tn3 * BK + 4);
            }
            mma(0);
            bfr_load(jtf(it + 1));
            sync_lds();
        }
        // ======== odd body: it = 2*it2+1, cb = 1 ========
        {
            const int it = it2 * 2 + 1;
            if (it + 1 < NITER) {
                stage(jtf(it + 1), 0, aA0, aA1);           // consume A (even tile)
                const int tn3 = jtf(it + 3);
                aA0 = *(const float4*)(adj_row + tn3 * BK);        // refill A
                aA1 = *(const float4*)(adj_row + tn3 * BK + 4);
            }
            mma(1);
            bfr_load(jtf(it + 1));
            sync_lds();
        }
    }

    // ---- epilogue: atomic accumulate l and O (zeroed before launch) ----
#pragma unroll
    for (int msk = 1; msk < 8; msk <<= 1) lsum += __shfl_xor(lsum, msk);
    if ((t & 7) == 0) unsafeAtomicAdd(&l[gr], lsum);

#pragma unroll
    for (int mt = 0; mt < 4; ++mt) {
#pragma unroll
        for (int nt = 0; nt < 2; ++nt) {
            f32x4 v = acc[mt][nt];
            int col = w * 32 + nt * 16 + lo;
#pragma unroll
            for (int reg = 0; reg < 4; ++reg) {
                int row = mt * 16 + quad * 4 + reg;
                unsafeAtomicAdd(&O[(size_t)(r0 + row) * D + col], v[reg]);
            }
        }
    }
}

// ---------------- K5: divide by l ----------------
__global__ __launch_bounds__(256) void k5_div(const float* __restrict__ O,
                                              const float* __restrict__ l,
                                              float* __restrict__ out) {
    const int idx = blockIdx.x * 256 + threadIdx.x;   // over N*D/4
    const int r = idx >> 6;                           // D/4 = 64 float4 per row
    f32x4 o = *(const f32x4*)(O + (size_t)idx * 4);
    const float inv = 1.f / l[r];
    *(f32x4*)(out + (size_t)idx * 4) = o * inv;
}

// ---------------- launch ----------------
extern "C" void kernel_launch(void* const* d_in, const int* in_sizes, int n_in,
                              void* d_out, int out_size, void* d_ws, size_t ws_size,
                              hipStream_t stream) {
    const float* x   = (const float*)d_in[0];   // [N, D]
    const float* adj = (const float*)d_in[1];   // [N, N]
    const float* W   = (const float*)d_in[2];   // [D, D]
    const float* a   = (const float*)d_in[3];   // [2*D]
    float* out = (float*)d_out;

    // ws layout (~24.5 MB):
    char* ws = (char*)d_ws;
    float* Wh            = (float*)(ws);                         // 8 MB
    unsigned short* WhT  = (unsigned short*)(ws + 8388608);      // 4 MB
    float* e_src         = (float*)(ws + 12582912);              // 32 KB
    float* e_dst         = (float*)(ws + 12615680);              // 32 KB
    float* O             = (float*)(ws + 16777216);              // 8 MB (N*D*4)
    float* l             = (float*)(ws + 16777216 + 8388608);    // 32 KB (N*4)

    // zero O + l (contiguous, one call; graph-capture-legal)
    hipMemsetAsync(ws + 16777216, 0, 8388608 + 32768, stream);

    k1_gemm<<<N / K1_BM, 256, 0, stream>>>(x, W, Wh, WhT);
    k2_edot<<<N / 4, 256, 0, stream>>>(Wh, a, e_src, e_dst);
    k4_main<<<RB * SPLITS, 512, 0, stream>>>(adj, WhT, e_src, e_dst, O, l);
    k5_div<<<N * D / 4 / 256, 256, 0, stream>>>(O, l, out);
}

// Round 8
// 444.488 us; speedup vs baseline: 1.0112x; 1.0112x over previous
//
#include <hip/hip_runtime.h>
#include <stdint.h>

#define N 8192
#define D 256
#define LOG2E 1.44269504f

typedef __attribute__((ext_vector_type(4))) float f32x4;
typedef __attribute__((ext_vector_type(8))) short bf16x8;

__device__ __forceinline__ unsigned short f2bf(float f) {
    unsigned u = __float_as_uint(f);
    u += 0x7fff + ((u >> 16) & 1);           // RNE
    return (unsigned short)(u >> 16);
}
__device__ __forceinline__ float leaky(float x) {
    return fmaxf(x, 0.f) + 0.2f * fminf(x, 0.f);
}
__device__ __forceinline__ float exp2_raw(float x) {   // v_exp_f32 = 2^x
    float r;
    asm("v_exp_f32 %0, %1" : "=v"(r) : "v"(x));
    return r;
}
// CK-style block_sync_lds: LDS-ordering barrier that does NOT drain vmcnt,
// so register-destination global prefetches stay in flight across it.
__device__ __forceinline__ void sync_lds() {
    asm volatile("s_waitcnt lgkmcnt(0)\n\ts_barrier" ::: "memory");
}

// ---------------- K1: Wh = x @ W (fp32), also write WhT bf16 [D][N] ----------------
// At its fp32 vector-FLOP roofline (~13.7us): no fp32-input MFMA on CDNA4.
#define K1_BM 16
__global__ __launch_bounds__(256) void k1_gemm(const float* __restrict__ x,
                                               const float* __restrict__ W,
                                               float* __restrict__ Wh,
                                               unsigned short* __restrict__ WhT) {
    __shared__ float xsT[32][20];   // [k][r]
    const int t = threadIdx.x;      // = output column
    const int r0 = blockIdx.x * K1_BM;
    float acc[K1_BM];
#pragma unroll
    for (int i = 0; i < K1_BM; ++i) acc[i] = 0.f;

    const int lr = t >> 3, lks = (t & 7) * 4;   // loader coords (t < 128)
    float4 xv;
    if (t < 128) xv = *(const float4*)(x + (size_t)(r0 + lr) * D + lks);

    for (int k0 = 0; k0 < D; k0 += 32) {
        __syncthreads();
        if (t < 128) {
            xsT[lks + 0][lr] = xv.x; xsT[lks + 1][lr] = xv.y;
            xsT[lks + 2][lr] = xv.z; xsT[lks + 3][lr] = xv.w;
        }
        __syncthreads();
        if (t < 128 && k0 + 32 < D)   // prefetch next K-tile; consumed next iter
            xv = *(const float4*)(x + (size_t)(r0 + lr) * D + k0 + 32 + lks);
#pragma unroll 8
        for (int kk = 0; kk < 32; ++kk) {
            float wv = W[(size_t)(k0 + kk) * D + t];
#pragma unroll
            for (int rc = 0; rc < K1_BM / 4; ++rc) {
                float4 xr = *(const float4*)&xsT[kk][rc * 4];
                acc[rc * 4 + 0] += xr.x * wv;
                acc[rc * 4 + 1] += xr.y * wv;
                acc[rc * 4 + 2] += xr.z * wv;
                acc[rc * 4 + 3] += xr.w * wv;
            }
        }
    }
#pragma unroll
    for (int r = 0; r < K1_BM; ++r) Wh[(size_t)(r0 + r) * D + t] = acc[r];
    unsigned short pk[K1_BM];
#pragma unroll
    for (int r = 0; r < K1_BM; ++r) pk[r] = f2bf(acc[r]);
    uint4* dst = (uint4*)(WhT + (size_t)t * N + r0);
    dst[0] = *(uint4*)&pk[0];
    dst[1] = *(uint4*)&pk[8];
}

// ---------------- K2: e_src / e_dst (wave per row), pre-scaled by log2(e) ----------------
__global__ __launch_bounds__(256) void k2_edot(const float* __restrict__ Wh,
                                               const float* __restrict__ a,
                                               float* __restrict__ e_src,
                                               float* __restrict__ e_dst) {
    const int wave = threadIdx.x >> 6, lane = threadIdx.x & 63;
    const int row = blockIdx.x * 4 + wave;
    float4 wv = *(const float4*)(Wh + (size_t)row * D + lane * 4);
    float4 as = *(const float4*)(a + lane * 4);
    float4 ad = *(const float4*)(a + D + lane * 4);
    float ps = wv.x * as.x + wv.y * as.y + wv.z * as.z + wv.w * as.w;
    float pd = wv.x * ad.x + wv.y * ad.y + wv.z * ad.z + wv.w * ad.w;
#pragma unroll
    for (int m = 1; m < 64; m <<= 1) {
        ps += __shfl_xor(ps, m);
        pd += __shfl_xor(pd, m);
    }
    if (lane == 0) { e_src[row] = ps * LOG2E; e_dst[row] = pd * LOG2E; }
}

// ---------------- K4: masked softmax + PV matmul ----------------
// v9 = exact v7 revert (best: 443.5us). v8's atomic-O epilogue regressed
// (+6us): 16.8M LLC-side f32 atomics + memset cost more than the 96MB
// streaming round-trip they replaced — streaming partials wins.
// k4's structural constraint (documented, twice-tested): P-tile LDS broadcast
// amplification (8KB tile x 8 reader waves = 64KB/block-iter, ~60-75% of the
// LDS pipe) can only shrink via >64-VGPR accumulators, which drops occupancy
// to 4 waves/SIMD — a trade that regressed in r1 and r4. All cheap levers
// (rotation de-phasing, stage->prefetch->mma order, setprio, stage diet,
// bank swizzle, ed_lds) are in and verified.
#define BM 64
#define BK 64
#define RB (N / BM)          // 128 row-blocks
#define SPLITS 8             // grid = RB*SPLITS = 1024
#define NITER ((N / SPLITS) / BK)   // 16
#define PSTRIDE 72           // ushorts per P row (144 B, 16B-aligned)
__global__ __launch_bounds__(512, 4) void k4_main(const float* __restrict__ adj,
                                                  const unsigned short* __restrict__ WhT,
                                                  const float* __restrict__ e_src,
                                                  const float* __restrict__ e_dst,
                                                  float* __restrict__ O_part,
                                                  float* __restrict__ l_part) {
    __shared__ unsigned short p_lds[2][BM][PSTRIDE];   // 18.4 KB P tile, dbuf
    __shared__ float ed_lds[N / SPLITS];               // 4 KB e_dst slice

    const int t = threadIdx.x;
    const int rb = blockIdx.x >> 3;          // row-block
    const int s  = blockIdx.x & 7;           // j-slice == XCD (round-robin heuristic)
    const int r0 = rb * BM;
    const int j0 = s * (N / SPLITS);
    const int rot = ((blockIdx.x >> 8) * 5) & (NITER - 1);   // de-phasing

    // P-generation coords: 8 threads per row, 8 cols each
    const int pr = t >> 3;            // 0..63
    const int pc = (t & 7) * 8;       // 0..56
    const int gr = r0 + pr;

    const int w = t >> 6;             // wave 0..7 -> output cols w*32..w*32+31
    const int lane = t & 63;
    const int quad = lane >> 4, lo = lane & 15;

    // bank-alias swizzle (bit5 ^= row-bit3), folded into constants:
    const int woff = (pc * 2) ^ ((pr & 8) << 2);                 // P-write byte offset
    const int roff0 = (quad * 16) ^ ((lo & 8) << 2);             // afr read, ks2=0
    const int roff1 = (64 + quad * 16) ^ ((lo & 8) << 2);        // afr read, ks2=1

    const float es = e_src[gr];       // already * LOG2E

    // diagonal bookkeeping: at most one (tile, element) per thread per pass
    const int dcol = gr - j0;
    const int dtile = dcol >> 6;
    const int djj = dcol & 7;
    const bool hd = ((unsigned)dcol < (unsigned)(N / SPLITS)) && ((dcol & 56) == pc);

    f32x4 acc[4][2];
#pragma unroll
    for (int mt = 0; mt < 4; ++mt)
#pragma unroll
        for (int nt = 0; nt < 2; ++nt)
            acc[mt][nt] = (f32x4){0.f, 0.f, 0.f, 0.f};
    float lsum = 0.f;

    const float* adj_row = adj + (size_t)gr * N + j0 + pc;
    // B-fragment base: row (= Wh col) = w*32 + nt*16 + lo, k offset = quad*8
    const unsigned short* wt_base = WhT + (size_t)(w * 32 + lo) * N + j0 + quad * 8;

    auto jtf = [&](int i) {
        int c = (i < NITER) ? i : NITER - 1;
        return (c + rot) & (NITER - 1);
    };

    float4 aA0, aA1;                  // adj buffer A: even logical tiles
    float4 aB0, aB1;                  // adj buffer B: odd logical tiles
    bf16x8 bfr[2][2];                 // [ks2][nt]

    auto mma = [&](int cb) {
        __builtin_amdgcn_s_setprio(1);
#pragma unroll
        for (int ks2 = 0; ks2 < 2; ++ks2) {
            bf16x8 afr[4];
#pragma unroll
            for (int mt = 0; mt < 4; ++mt) {
                const char* arow = (const char*)&p_lds[cb][mt * 16 + lo][0];
                afr[mt] = *(const bf16x8*)(arow + (ks2 ? roff1 : roff0));
            }
#pragma unroll
            for (int nt = 0; nt < 2; ++nt)
#pragma unroll
                for (int mt = 0; mt < 4; ++mt)
                    acc[mt][nt] = __builtin_amdgcn_mfma_f32_16x16x32_bf16(
                        afr[mt], bfr[ks2][nt], acc[mt][nt], 0, 0, 0);
        }
        __builtin_amdgcn_s_setprio(0);
    };
    auto bfr_load = [&](int tile) {
#pragma unroll
        for (int ks2 = 0; ks2 < 2; ++ks2)
#pragma unroll
            for (int nt = 0; nt < 2; ++nt)
                bfr[ks2][nt] = *(const bf16x8*)(wt_base + (size_t)nt * (16 * N) +
                                                tile * BK + ks2 * 32);
    };
    // stage: P for rotated tile `tile` from adj regs + ed_lds -> p_lds[buf]
    auto stage = [&](int tile, int buf, float4 a0, float4 a1) {
        f32x4 e0 = *(const f32x4*)&ed_lds[tile * BK + pc];
        f32x4 e1 = *(const f32x4*)&ed_lds[tile * BK + pc + 4];
        float av[8] = {a0.x, a0.y, a0.z, a0.w, a1.x, a1.y, a1.z, a1.w};
        float ev[8] = {e0[0], e0[1], e0[2], e0[3], e1[0], e1[1], e1[2], e1[3]};
        float pv[8];
#pragma unroll
        for (int jj = 0; jj < 8; ++jj)
            pv[jj] = exp2_raw(leaky(es + ev[jj])) * av[jj];   // adj is exactly 0/1
        if (hd && tile == dtile)      // rare: force-keep the diagonal element
            pv[djj] = exp2_raw(leaky(es + ev[djj]));
#pragma unroll
        for (int jj = 0; jj < 8; ++jj) lsum += pv[jj];
        unsigned wpk[4];
#pragma unroll
        for (int jj = 0; jj < 4; ++jj)
            asm("v_cvt_pk_bf16_f32 %0, %1, %2"
                : "=v"(wpk[jj]) : "v"(pv[2 * jj]), "v"(pv[2 * jj + 1]));
        char* prow = (char*)&p_lds[buf][pr][0];
        *(uint4*)(prow + woff) = *(uint4*)wpk;
    };

    // ---- prologue ----
    {
        ((float2*)ed_lds)[t] = ((const float2*)(e_dst + j0))[t];   // ed slice -> LDS
        const int t0 = jtf(0), t1 = jtf(1), t2 = jtf(2);
        aA0 = *(const float4*)(adj_row + t0 * BK);
        aA1 = *(const float4*)(adj_row + t0 * BK + 4);
        aB0 = *(const float4*)(adj_row + t1 * BK);
        aB1 = *(const float4*)(adj_row + t1 * BK + 4);
        bfr_load(t0);
        __syncthreads();                 // ed_lds visible
        stage(t0, 0, aA0, aA1);
        aA0 = *(const float4*)(adj_row + t2 * BK);         // adj tile 2 -> A
        aA1 = *(const float4*)(adj_row + t2 * BK + 4);
    }
    sync_lds();

    for (int it2 = 0; it2 < NITER / 2; ++it2) {
        // ======== even body: it = 2*it2, cb = 0 ========
        {
            const int it = it2 * 2;
            stage(jtf(it + 1), 1, aB0, aB1);               // consume B (odd tile)
            {
                const int tn3 = jtf(it + 3);
                aB0 = *(const float4*)(adj_row + tn3 * BK);        // refill B
                aB1 = *(const float4*)(adj_row + tn3 * BK + 4);
            }
            mma(0);
            bfr_load(jtf(it + 1));
            sync_lds();
        }
        // ======== odd body: it = 2*it2+1, cb = 1 ========
        {
            const int it = it2 * 2 + 1;
            if (it + 1 < NITER) {
                stage(jtf(it + 1), 0, aA0, aA1);           // consume A (even tile)
                const int tn3 = jtf(it + 3);
                aA0 = *(const float4*)(adj_row + tn3 * BK);        // refill A
                aA1 = *(const float4*)(adj_row + tn3 * BK + 4);
            }
            mma(1);
            bfr_load(jtf(it + 1));
            sync_lds();
        }
    }

    // ---- epilogue ----
#pragma unroll
    for (int msk = 1; msk < 8; msk <<= 1) lsum += __shfl_xor(lsum, msk);
    if ((t & 7) == 0) l_part[(size_t)s * N + gr] = lsum;

#pragma unroll
    for (int mt = 0; mt < 4; ++mt) {
#pragma unroll
        for (int nt = 0; nt < 2; ++nt) {
            f32x4 v = acc[mt][nt];
            int col = w * 32 + nt * 16 + lo;
#pragma unroll
            for (int reg = 0; reg < 4; ++reg) {
                int row = mt * 16 + quad * 4 + reg;
                O_part[((size_t)s * N + r0 + row) * D + col] = v[reg];
            }
        }
    }
}

// ---------------- K5: reduce partials (float4), divide by l ----------------
__global__ __launch_bounds__(256) void k5_reduce(const float* __restrict__ O_part,
                                                 const float* __restrict__ l_part,
                                                 float* __restrict__ out) {
    const int idx = blockIdx.x * 256 + threadIdx.x;   // over N*D/4
    const int r = idx >> 6;                           // D/4 = 64 float4 per row
    float lsum = 0.f;
#pragma unroll
    for (int s = 0; s < SPLITS; ++s) lsum += l_part[(size_t)s * N + r];
    f32x4 o = (f32x4){0.f, 0.f, 0.f, 0.f};
#pragma unroll
    for (int s = 0; s < SPLITS; ++s)
        o += *(const f32x4*)(O_part + (size_t)s * N * D + (size_t)idx * 4);
    const float inv = 1.f / lsum;
    *(f32x4*)(out + (size_t)idx * 4) = o * inv;
}

// ---------------- launch ----------------
extern "C" void kernel_launch(void* const* d_in, const int* in_sizes, int n_in,
                              void* d_out, int out_size, void* d_ws, size_t ws_size,
                              hipStream_t stream) {
    const float* x   = (const float*)d_in[0];   // [N, D]
    const float* adj = (const float*)d_in[1];   // [N, N]
    const float* W   = (const float*)d_in[2];   // [D, D]
    const float* a   = (const float*)d_in[3];   // [2*D]
    float* out = (float*)d_out;

    // ws layout (~80.1 MB):
    char* ws = (char*)d_ws;
    float* Wh            = (float*)(ws);                         // 8 MB
    unsigned short* WhT  = (unsigned short*)(ws + 8388608);      // 4 MB
    float* e_src         = (float*)(ws + 12582912);              // 32 KB
    float* e_dst         = (float*)(ws + 12615680);              // 32 KB
    float* l_part        = (float*)(ws + 12648704);              // 256 KB (SPLITS*N*4)
    float* O_part        = (float*)(ws + 16777216);              // 64 MB (SPLITS*N*D*4)

    k1_gemm<<<N / K1_BM, 256, 0, stream>>>(x, W, Wh, WhT);
    k2_edot<<<N / 4, 256, 0, stream>>>(Wh, a, e_src, e_dst);
    k4_main<<<RB * SPLITS, 512, 0, stream>>>(adj, WhT, e_src, e_dst, O_part, l_part);
    k5_reduce<<<N * D / 4 / 256, 256, 0, stream>>>(O_part, l_part, out);
}